// Round 1
// baseline (250.833 us; speedup 1.0000x reference)
//
#include <hip/hip_runtime.h>
#include <math.h>

// Problem constants (from reference): B=8, S=128, V=32000, K=32.
constexpr int Bc = 8, Sc = 128, Vc = 32000, Kc = 32;
constexpr int NT = 1024;            // threads per block (16 waves)
constexpr int V4 = Vc / 4;          // 8000 float4 per row
constexpr int ITERS = (V4 + NT - 1) / NT;  // 8
constexpr int NWAVES = NT / 64;     // 16

// One block per (b,s) row. Row (32000 f32) held register-resident as 8 x float4
// per thread -> single global read + single global write (262 MB total, mem-bound).
__global__ __launch_bounds__(NT) void SR_knnModel_kernel(
    const float* __restrict__ logit,        // [B,S,V]
    const int*   __restrict__ optor_vals,   // [B,S,K]
    const float* __restrict__ optor_dists,  // [B,S,K]
    const int*   __restrict__ const_vals,   // [B,S,K]
    const float* __restrict__ const_dists,  // [B,S,K]
    const int*   __restrict__ prev_words,   // [B,S]
    const float* __restrict__ optor_lamda,  // [1]
    const float* __restrict__ const_lamda,  // [1]
    const float* __restrict__ optor_temp,   // [1]
    const float* __restrict__ const_temp,   // [1]
    float* __restrict__ out)                // [B,S,V]
{
    const int row = blockIdx.x;             // b*S + s
    const int t   = threadIdx.x;
    const size_t base = (size_t)row * Vc;
    const float4* __restrict__ xin  = (const float4*)(logit + base);
    float4* __restrict__       xout = (float4*)(out + base);

    // ---- Phase 1: load row into registers, thread-local max ----
    float4 r[ITERS];
    float lmax = -INFINITY;
#pragma unroll
    for (int i = 0; i < ITERS; ++i) {
        const int idx = t + i * NT;
        if (i < ITERS - 1 || idx < V4) {    // folds to `true` for i<7
            const float4 v = xin[idx];
            r[i] = v;
            lmax = fmaxf(lmax, fmaxf(fmaxf(v.x, v.y), fmaxf(v.z, v.w)));
        }
    }

    // ---- block-reduce max (wave shuffle -> LDS -> broadcast) ----
    __shared__ float red[NWAVES];
#pragma unroll
    for (int off = 32; off > 0; off >>= 1)
        lmax = fmaxf(lmax, __shfl_xor(lmax, off));
    const int wave = t >> 6;
    if ((t & 63) == 0) red[wave] = lmax;
    __syncthreads();
    float bmax = red[0];
#pragma unroll
    for (int w = 1; w < NWAVES; ++w) bmax = fmaxf(bmax, red[w]);
    __syncthreads();                        // before reusing `red` for the sum

    // ---- Phase 2: exp in-place, thread-local sum ----
    float lsum = 0.f;
#pragma unroll
    for (int i = 0; i < ITERS; ++i) {
        const int idx = t + i * NT;
        if (i < ITERS - 1 || idx < V4) {
            float4 v = r[i];
            v.x = __expf(v.x - bmax);
            v.y = __expf(v.y - bmax);
            v.z = __expf(v.z - bmax);
            v.w = __expf(v.w - bmax);
            r[i] = v;
            lsum += (v.x + v.y) + (v.z + v.w);
        }
    }
#pragma unroll
    for (int off = 32; off > 0; off >>= 1)
        lsum += __shfl_xor(lsum, off);
    if ((t & 63) == 0) red[wave] = lsum;
    __syncthreads();
    float bsum = 0.f;
#pragma unroll
    for (int w = 0; w < NWAVES; ++w) bsum += red[w];

    // ---- per-row scalars (masks are mutually exclusive in practice, but we
    // implement the fully-general linear combination from the reference) ----
    const int pw = prev_words[row];
    const bool om = (pw <= 88) || (pw >= 91 && pw <= 291);
    const bool cm = (pw == 89) || (pw == 90) || (pw >= 292);
    const float omf = om ? 1.f : 0.f;
    const float cmf = cm ? 1.f : 0.f;
    const float ol = optor_lamda[0];
    const float cl = const_lamda[0];
    const float cn = (1.f - ol) * omf + (1.f - cl) * cmf;   // coeff on nmt_prob
    const float inv = cn / bsum;

    // ---- Phase 3: scale + store ----
#pragma unroll
    for (int i = 0; i < ITERS; ++i) {
        const int idx = t + i * NT;
        if (i < ITERS - 1 || idx < V4) {
            float4 v = r[i];
            v.x *= inv; v.y *= inv; v.z *= inv; v.w *= inv;
            xout[idx] = v;
        }
    }
    __syncthreads();   // drains vmcnt -> bulk stores visible at L2 before atomics

    // ---- kNN scatter: wave0 lanes 0..31 = optor, wave1 lanes 0..31 = const.
    // softmax over K=32 of -d/temp, then atomicAdd(lam*mask*w) at val positions.
    if (t < 32 || (t >= 64 && t < 96)) {
        const bool is_opt = (t < 32);
        const float scale = is_opt ? ol * omf : cl * cmf;
        if (scale != 0.f) {                 // wave-uniform branch
            const int k = t & 31;
            const int*   vals  = is_opt ? optor_vals  : const_vals;
            const float* dists = is_opt ? optor_dists : const_dists;
            const float  temp  = is_opt ? optor_temp[0] : const_temp[0];
            const float s = -dists[row * Kc + k] / temp;
            float m = s;
#pragma unroll
            for (int off = 16; off > 0; off >>= 1)
                m = fmaxf(m, __shfl_xor(m, off));
            const float e = __expf(s - m);
            float sm = e;
#pragma unroll
            for (int off = 16; off > 0; off >>= 1)
                sm += __shfl_xor(sm, off);
            const float w = e / sm;
            atomicAdd(out + base + vals[row * Kc + k], scale * w);
        }
    }
}

extern "C" void kernel_launch(void* const* d_in, const int* in_sizes, int n_in,
                              void* d_out, int out_size, void* d_ws, size_t ws_size,
                              hipStream_t stream) {
    const float* logit       = (const float*)d_in[0];
    const int*   optor_vals  = (const int*)  d_in[1];
    const float* optor_dists = (const float*)d_in[2];
    const int*   const_vals  = (const int*)  d_in[3];
    const float* const_dists = (const float*)d_in[4];
    const int*   prev_words  = (const int*)  d_in[5];
    const float* optor_lamda = (const float*)d_in[6];
    const float* const_lamda = (const float*)d_in[7];
    const float* optor_temp  = (const float*)d_in[8];
    const float* const_temp  = (const float*)d_in[9];
    float* out = (float*)d_out;

    SR_knnModel_kernel<<<Bc * Sc, NT, 0, stream>>>(
        logit, optor_vals, optor_dists, const_vals, const_dists, prev_words,
        optor_lamda, const_lamda, optor_temp, const_temp, out);
}